// Round 4
// baseline (466.782 us; speedup 1.0000x reference)
//
#include <hip/hip_runtime.h>
#include <hip/hip_bf16.h>

// ModulationConvBlock: per-sample modulated/demodulated 3x3 conv.
// fp32 in/out, bf16 MFMA internally. B=8, IN_C=OUT_C=256, H=W=128, K=3.
//
// Round-9: (1) k_transpose ELIMINATED — k_conv stages X directly from fp32 NCHW
//          (16 strided dword loads/thread, f2bf in reg, same b128 LDS writes);
//          (2) 4 waves, acc[4][4] (0.5 LDS reads/MFMA — LDS-unit was the
//          saturated resource); (3) conflict-free swizzle perm=(row>>1)&3
//          (hand-verified 2 lanes/16B-chunk for all read+write patterns).
//
// ws layout: Wt 9.00 MiB | norm2 8 KiB   (no Xt anymore)

typedef __attribute__((ext_vector_type(8))) short short8;
typedef __attribute__((ext_vector_type(4))) float floatx4;
typedef __bf16 bf16x8 __attribute__((ext_vector_type(8)));

#define B_    8
#define IC_   256
#define OC_   256
#define HW_   128
#define PIX_  (HW_*HW_)
#define RTOT  2304                  // 9*256, k-order: tap-major, ic-minor
#define WSCALE (1.0f/48.0f)         // 1/sqrt(3*3*256)

// XOR swizzle: 8-elem (16B) slot within a 32-elem (64B) row, keyed on row bits 1..2.
// chunk(l) = (4*row(l) + slot) mod 8 is exactly 2-per-chunk over any 16 consecutive
// rows for both the frag-read pattern (row=base+l15) and the staging-write pattern
// (row=tid>>1, 2 b128/thread). 2-way is the free minimum for wave64 on 32 banks.
#define SWZ(row) ((((row) >> 1) & 3) << 3)

static __device__ __forceinline__ floatx4 mfma_bf16(short8 a, short8 b, floatx4 c) {
  return __builtin_amdgcn_mfma_f32_16x16x32_bf16(
      __builtin_bit_cast(bf16x8, a), __builtin_bit_cast(bf16x8, b), c, 0, 0, 0);
}

static __device__ __forceinline__ unsigned short f2bf(float f) {
  unsigned int u = __builtin_bit_cast(unsigned int, f);
  return (unsigned short)(u >> 16) + (unsigned short)((u >> 15) & 1u);
}

// ---------------- Z: zero norm2 ----------------
__global__ __launch_bounds__(256) void k_zero(float* __restrict__ p, int n) {
  int i = blockIdx.x * 256 + threadIdx.x;
  if (i < n) p[i] = 0.f;
}

// ---------------- A1: demod norms (fp32) ----------------
__global__ __launch_bounds__(256) void k_norm(const float* __restrict__ Wraw,
                                              const float* __restrict__ code,
                                              float* __restrict__ norm2) {
  const int tap = blockIdx.x % 9, b = blockIdx.x / 9;
  const int oc = threadIdx.x;
  __shared__ float cs[IC_];
  cs[oc] = code[b * IC_ + oc];
  __syncthreads();
  float s = 0.f;
#pragma unroll 8
  for (int ic = 0; ic < IC_; ++ic) {
    float v = Wraw[(size_t)(tap * IC_ + ic) * OC_ + oc] * cs[ic];
    s += v * v;
  }
  atomicAdd(&norm2[b * OC_ + oc], s * (WSCALE * WSCALE));
}

// ---------------- A2: write modulated+demodulated weights (bf16) ----------------
__global__ __launch_bounds__(256) void k_modw(const float* __restrict__ Wraw,
                                              const float* __restrict__ code,
                                              const float* __restrict__ norm2,
                                              unsigned short* __restrict__ Wt) {
  const int idx = blockIdx.x * 256 + threadIdx.x;   // idx = ((b*256 + oc)*2304 + r)
  const int r  = idx % RTOT;
  const int t2 = idx / RTOT;
  const int oc = t2 & 255;
  const int b  = t2 >> 8;
  const int ic = r & 255;
  const float w  = Wraw[(size_t)r * OC_ + oc];
  const float cd = code[b * IC_ + ic];
  const float rn = rsqrtf(norm2[b * OC_ + oc] + 1e-8f);
  Wt[idx] = f2bf(w * cd * WSCALE * rn);
}

// ---------------- K3: implicit-GEMM conv, fused X-transpose, pipelined -----------
// Block = 128oc x 128px (one image row), 256 threads / 4 waves.
// Wave w: wm=w&1 (64-oc half), wn=w>>1 (64-px half). acc[4][4], 48 MFMA/stage/wave.
// Stage s = (iy, icc): X staged DIRECTLY from fp32 NCHW x (16 strided dwords/thread,
// coalesced 128B per half-wave along px), W from precomputed bf16 Wt.
// Pipeline: CLOAD(s+1) -> MFMAs (setprio) on buf(s&1) -> cvt+DSW buf(s&1^1) -> barrier.
__global__ __launch_bounds__(256, 2) void k_conv(const float* __restrict__ x,
                                                 const unsigned short* __restrict__ Wt,
                                                 const float* __restrict__ bias,
                                                 float* __restrict__ out) {
  __shared__ __align__(16) unsigned short Wl[2][3][128 * 32];   // 48 KiB
  __shared__ __align__(16) unsigned short Xl[2][130 * 32];      // 16.25 KiB

  const int tid  = threadIdx.x;
  const int lane = tid & 63;
  const int wv   = tid >> 6;          // wave id 0..3
  const int wm   = wv & 1;            // oc-half (64)
  const int wn   = wv >> 1;           // px-half (64)
  const int l15  = lane & 15;
  const int k0   = (lane >> 4) * 8;   // frag k-offset (elements)

  // T1: bijective XCD-chunk block swizzle (nwg = 2048); one XCD owns one image.
  const int nwg  = (int)(gridDim.x * gridDim.y * gridDim.z);
  const int q    = nwg >> 3;
  const int flat = (int)(blockIdx.x + gridDim.x * (blockIdx.y + gridDim.y * blockIdx.z));
  const int nf   = (flat & 7) * q + (flat >> 3);
  const int py = nf & 127, ot = (nf >> 7) & 1, b = nf >> 8;

  const unsigned short* Wtp = Wt + (size_t)(b * OC_ + ot * 128) * RTOT;
  const float* xb = x + (size_t)b * IC_ * PIX_;

  // staging thread mapping: 2 threads per row, one 16-elem half each
  const int srow = tid >> 1;          // 0..127 (X row = srow+1 (px=srow); W row = oc_local)
  const int xh   = tid & 1;           // 16-elem half
  const int sW   = SWZ(srow);         // W write swizzle (row = srow)
  const int sX   = SWZ(srow + 1);     // X write swizzle (row = srow+1)
  const int eW0  = (xh * 16) ^ sW;    // swizzled slot of first 8 elems
  const int eX0  = (xh * 16) ^ sX;

  // read-side swizzles (low 4 row bits come from l15 [+kx] only)
  const int sA  = SWZ(l15);
  const int sB0 = SWZ(l15), sB1 = SWZ(l15 + 1), sB2 = SWZ(l15 + 2);

  const int lo = (py > 0) ? py - 1 : 0;
  const int hi = (py < HW_ - 1) ? py + 1 : HW_ - 1;
  const int NS = (hi - lo + 1) * 8;   // 16 or 24, block-uniform

  const floatx4 zz = {0.f, 0.f, 0.f, 0.f};
  floatx4 acc[4][4];
#pragma unroll
  for (int i = 0; i < 4; ++i)
#pragma unroll
    for (int j = 0; j < 4; ++j) acc[i][j] = zz;

  // zero padding rows (px=-1 -> row 0, px=128 -> row 129) of BOTH buffers
  if (tid < 128) {
    const int bi = tid >> 6, rr = tid & 63;
    const int r = (rr < 32) ? 0 : 129;
    Xl[bi][r * 32 + (rr & 31)] = 0;
  }

  float xr[16];
  short8 wr0, wr1, wr2, wr3, wr4, wr5;

#define CLOAD(s_) do {                                                           \
    const int iy_   = lo + ((s_) >> 3);                                          \
    const int icc_  = (s_) & 7;                                                  \
    const int tapb_ = (iy_ - py + 1) * 3;                                        \
    const float* xs_ = xb + (size_t)(icc_ * 32 + xh * 16) * PIX_ + iy_ * HW_ + srow; \
    _Pragma("unroll")                                                            \
    for (int i_ = 0; i_ < 16; ++i_) xr[i_] = xs_[(size_t)i_ * PIX_];             \
    const unsigned short* ws_ =                                                  \
        Wtp + (size_t)srow * RTOT + (size_t)tapb_ * IC_ + icc_ * 32 + xh * 16;   \
    wr0 = *(const short8*)(ws_);                                                 \
    wr1 = *(const short8*)(ws_ + 8);                                             \
    wr2 = *(const short8*)(ws_ + IC_);                                           \
    wr3 = *(const short8*)(ws_ + IC_ + 8);                                       \
    wr4 = *(const short8*)(ws_ + 2 * IC_);                                       \
    wr5 = *(const short8*)(ws_ + 2 * IC_ + 8);                                   \
  } while (0)

#define DSW(b_) do {                                                             \
    short8 p0_, p1_;                                                             \
    _Pragma("unroll")                                                            \
    for (int c_ = 0; c_ < 8; ++c_) {                                             \
      p0_[c_] = (short)f2bf(xr[c_]);                                             \
      p1_[c_] = (short)f2bf(xr[8 + c_]);                                         \
    }                                                                            \
    unsigned short* xd_ = &Xl[b_][(srow + 1) * 32];                              \
    *(short8*)(&xd_[eX0])     = p0_;                                             \
    *(short8*)(&xd_[eX0 ^ 8]) = p1_;                                             \
    unsigned short* wd0_ = &Wl[b_][0][srow * 32];                                \
    unsigned short* wd1_ = &Wl[b_][1][srow * 32];                                \
    unsigned short* wd2_ = &Wl[b_][2][srow * 32];                                \
    *(short8*)(&wd0_[eW0])     = wr0;                                            \
    *(short8*)(&wd0_[eW0 ^ 8]) = wr1;                                            \
    *(short8*)(&wd1_[eW0])     = wr2;                                            \
    *(short8*)(&wd1_[eW0 ^ 8]) = wr3;                                            \
    *(short8*)(&wd2_[eW0])     = wr4;                                            \
    *(short8*)(&wd2_[eW0 ^ 8]) = wr5;                                            \
  } while (0)

  // prologue: stage 0 into buf 0
  CLOAD(0);
  DSW(0);
  __syncthreads();

  for (int s = 0; s < NS; ++s) {
    const int nb = s & 1;
    if (s + 1 < NS) CLOAD(s + 1);     // issue next-stage global loads

    __builtin_amdgcn_s_setprio(1);
#pragma unroll
    for (int kx = 0; kx < 3; ++kx) {
      const int sB = (kx == 0) ? sB0 : (kx == 1) ? sB1 : sB2;
      short8 af[4], bfr[4];
#pragma unroll
      for (int i = 0; i < 4; ++i)
        af[i] = *(const short8*)(&Wl[nb][kx][(wm * 64 + i * 16 + l15) * 32 + (k0 ^ sA)]);
#pragma unroll
      for (int j = 0; j < 4; ++j)
        bfr[j] = *(const short8*)(&Xl[nb][(wn * 64 + j * 16 + l15 + kx) * 32 + (k0 ^ sB)]);
#pragma unroll
      for (int i = 0; i < 4; ++i)
#pragma unroll
        for (int j = 0; j < 4; ++j)
          acc[i][j] = mfma_bf16(af[i], bfr[j], acc[i][j]);
    }
    __builtin_amdgcn_s_setprio(0);

    if (s + 1 < NS) DSW(nb ^ 1);      // convert + write-late into the other buffer
    __syncthreads();                  // ONE barrier per stage
  }

#undef CLOAD
#undef DSW

  // epilogue: bias + LeakyReLU(0.2)*sqrt(2); C/D: col=lane&15 (px), row=(lane>>4)*4+p (oc)
  const int row0 = (lane >> 4) * 4;
#pragma unroll
  for (int i = 0; i < 4; ++i) {
#pragma unroll
    for (int p = 0; p < 4; ++p) {
      const int oc = ot * 128 + wm * 64 + i * 16 + row0 + p;
      const float bvf = bias[oc];
#pragma unroll
      for (int j = 0; j < 4; ++j) {
        const int px = wn * 64 + j * 16 + l15;
        float v = acc[i][j][p] + bvf;
        v = (v >= 0.f ? v : 0.2f * v) * 1.41421356237f;
        out[((size_t)(b * OC_ + oc) * HW_ + py) * HW_ + px] = v;   // fp32 store
      }
    }
  }
}

extern "C" void kernel_launch(void* const* d_in, const int* in_sizes, int n_in,
                              void* d_out, int out_size, void* d_ws, size_t ws_size,
                              hipStream_t stream) {
  const float* x    = (const float*)d_in[0];   // fp32 [8,256,128,128]
  const float* code = (const float*)d_in[1];   // fp32 [8,256]
  const float* wgt  = (const float*)d_in[2];   // fp32 [256,256,3,3] flat
  const float* bias = (const float*)d_in[3];   // fp32 [256]

  const size_t WT_BYTES = (size_t)B_ * OC_ * RTOT * 2;   // 9,437,184

  unsigned short* Wt = (unsigned short*)d_ws;
  float* norm2       = (float*)((char*)d_ws + WT_BYTES);

  k_zero<<<(B_ * OC_ + 255) / 256, 256, 0, stream>>>(norm2, B_ * OC_);
  k_norm<<<B_ * 9, 256, 0, stream>>>(wgt, code, norm2);
  k_modw<<<(B_ * OC_ * RTOT) / 256, 256, 0, stream>>>(wgt, code, norm2, Wt);
  k_conv<<<dim3(HW_, 2, B_), 256, 0, stream>>>(x, Wt, bias, (float*)d_out);
}

// Round 7
// 441.291 us; speedup vs baseline: 1.0578x; 1.0578x over previous
//
#include <hip/hip_runtime.h>
#include <hip/hip_bf16.h>

// ModulationConvBlock: per-sample modulated/demodulated 3x3 conv.
// fp32 in/out, bf16 MFMA internally. B=8, IN_C=OUT_C=256, H=W=128, K=3.
//
// Round-10 (2nd resubmit; broker timeouts): W bypasses LDS entirely — Wt
// stored in MFMA-fragment order so each A-frag is a coalesced 1KB dwordx4
// wave-load from L2 (per-XCD W set = 1.18MB). X: fused NCHW->bf16 staging with
// 2-DEEP register prefetch (xrA/xrB) so HBM latency (~900cy) is covered by ~2
// stage-bodies before the DSW vmcnt wait. LDS per stage: 8 X-writes + 48
// B-reads = 672 cyc < MFMA 931 -> MFMA-bound. ot on nf bit0: oc-halves of same
// py time-adjacent -> x rows fetched ~once (L2).
//
// ws layout: Wt2 9.00 MiB | norm2 8 KiB

typedef __attribute__((ext_vector_type(8))) short short8;
typedef __attribute__((ext_vector_type(4))) float floatx4;
typedef __bf16 bf16x8 __attribute__((ext_vector_type(8)));

#define B_    8
#define IC_   256
#define OC_   256
#define HW_   128
#define PIX_  (HW_*HW_)
#define RTOT  2304                  // 9*256
#define WSCALE (1.0f/48.0f)         // 1/sqrt(3*3*256)
#define WT2_PER_B (RTOT * OC_)      // 589824 elems per batch

// XOR swizzle (verified 0 conflicts in round-4 PMC): 16B slot within 64B row,
// keyed on row bits 1..2.
#define SWZ(row) ((((row) >> 1) & 3) << 3)

static __device__ __forceinline__ floatx4 mfma_bf16(short8 a, short8 b, floatx4 c) {
  return __builtin_amdgcn_mfma_f32_16x16x32_bf16(
      __builtin_bit_cast(bf16x8, a), __builtin_bit_cast(bf16x8, b), c, 0, 0, 0);
}

static __device__ __forceinline__ unsigned short f2bf(float f) {
  unsigned int u = __builtin_bit_cast(unsigned int, f);
  return (unsigned short)(u >> 16) + (unsigned short)((u >> 15) & 1u);
}

// ---------------- Z: zero norm2 ----------------
__global__ __launch_bounds__(256) void k_zero(float* __restrict__ p, int n) {
  int i = blockIdx.x * 256 + threadIdx.x;
  if (i < n) p[i] = 0.f;
}

// ---------------- A1: demod norms (fp32) ----------------
__global__ __launch_bounds__(256) void k_norm(const float* __restrict__ Wraw,
                                              const float* __restrict__ code,
                                              float* __restrict__ norm2) {
  const int tap = blockIdx.x % 9, b = blockIdx.x / 9;
  const int oc = threadIdx.x;
  __shared__ float cs[IC_];
  cs[oc] = code[b * IC_ + oc];
  __syncthreads();
  float s = 0.f;
#pragma unroll 8
  for (int ic = 0; ic < IC_; ++ic) {
    float v = Wraw[(size_t)(tap * IC_ + ic) * OC_ + oc] * cs[ic];
    s += v * v;
  }
  atomicAdd(&norm2[b * OC_ + oc], s * (WSCALE * WSCALE));
}

// ---------------- A2: modulated weights -> MFMA-fragment-ordered Wt2 -------------
// Layout: idx bits  e:0-2 | l15:3-6 | kg:7-8 | og:9-12 | icc:13-15 | (b*9+tap):16+
// so a wave's A-frag read (lane l: l15 = oc%16, kg = l>>4) is 1KB contiguous.
__global__ __launch_bounds__(256) void k_modw(const float* __restrict__ Wraw,
                                              const float* __restrict__ code,
                                              const float* __restrict__ norm2,
                                              unsigned short* __restrict__ Wt2) {
  const int idx = blockIdx.x * 256 + threadIdx.x;
  const int e   = idx & 7;
  const int l15 = (idx >> 3) & 15;
  const int kg  = (idx >> 7) & 3;
  const int og  = (idx >> 9) & 15;
  const int icc = (idx >> 13) & 7;
  const int bt  = idx >> 16;            // b*9 + tap, < 72
  const int b   = bt / 9;
  const int tap = bt - b * 9;
  const int oc  = og * 16 + l15;
  const int ic  = icc * 32 + kg * 8 + e;
  const float w  = Wraw[(size_t)(tap * IC_ + ic) * OC_ + oc];
  const float cd = code[b * IC_ + ic];
  const float rn = rsqrtf(norm2[b * OC_ + oc] + 1e-8f);
  Wt2[idx] = f2bf(w * cd * WSCALE * rn);
}

// ---------------- K3: implicit-GEMM conv, W-in-reg, 2-deep X prefetch ------------
// Block = 128oc x 128px (one image row), 256 threads / 4 waves (wm x wn = 2x2).
// Stage s = (iy, icc). A-frags: 12 coalesced dwordx4 global loads/wave (L2-hot),
// 1 stage ahead. X: 16 NCHW dwords/thread, 2 stages ahead, f2bf in reg,
// 2 swizzled b128 LDS writes. LDS holds only X (33 KB, double-buffered).
__global__ __launch_bounds__(256, 2) void k_conv(const float* __restrict__ x,
                                                 const unsigned short* __restrict__ Wt2,
                                                 const float* __restrict__ bias,
                                                 float* __restrict__ out) {
  __shared__ __align__(16) unsigned short Xl[2][130 * 32];      // 16.25 KiB x2

  const int tid  = threadIdx.x;
  const int lane = tid & 63;
  const int wv   = tid >> 6;          // wave id 0..3
  const int wm   = wv & 1;            // oc-half (64)
  const int wn   = wv >> 1;           // px-half (64)
  const int l15  = lane & 15;
  const int k0   = (lane >> 4) * 8;   // frag k-offset (elements)

  // T1 swizzle; ot on bit0 so both oc-halves of a py are time-adjacent (x reuse).
  const int nwg  = (int)(gridDim.x * gridDim.y * gridDim.z);   // 2048
  const int q    = nwg >> 3;
  const int flat = (int)(blockIdx.x + gridDim.x * (blockIdx.y + gridDim.y * blockIdx.z));
  const int nf   = (flat & 7) * q + (flat >> 3);
  const int ot = nf & 1, py = (nf >> 1) & 127, b = nf >> 8;

  const unsigned short* wb2 = Wt2 + (size_t)b * WT2_PER_B;
  const float* xb = x + (size_t)b * IC_ * PIX_;

  // X staging mapping: 2 threads per px-row, 16 channels each
  const int srow = tid >> 1;          // px 0..127  (Xl row = srow+1)
  const int xh   = tid & 1;           // channel half (16 ch)
  const int sX   = SWZ(srow + 1);
  const int eX0  = (xh * 16) ^ sX;

  // W frag addressing
  const int ogb  = ot * 8 + wm * 4;   // 16-oc group base for this wave
  const int wlo  = lane * 8;          // elem offset within 512-elem frag block

  // read-side swizzles
  const int sB0 = SWZ(l15), sB1 = SWZ(l15 + 1), sB2 = SWZ(l15 + 2);

  const int lo = (py > 0) ? py - 1 : 0;
  const int hi = (py < HW_ - 1) ? py + 1 : HW_ - 1;
  const int NS = (hi - lo + 1) * 8;   // 16 or 24 (always even), block-uniform

  const floatx4 zz = {0.f, 0.f, 0.f, 0.f};
  floatx4 acc[4][4];
#pragma unroll
  for (int i = 0; i < 4; ++i)
#pragma unroll
    for (int j = 0; j < 4; ++j) acc[i][j] = zz;

  // zero padding rows (px=-1 -> row 0, px=128 -> row 129) of BOTH buffers
  if (tid < 128) {
    const int bi = tid >> 6, rr = tid & 63;
    const int r = (rr < 32) ? 0 : 129;
    Xl[bi][r * 32 + (rr & 31)] = 0;
  }

  float xrA[16], xrB[16];
  short8 wA[12], wB[12];

#define XL(t_, XR_) do { if ((t_) < NS) {                                        \
    const int iy_  = lo + ((t_) >> 3);                                           \
    const int icc_ = (t_) & 7;                                                   \
    const float* xs_ = xb + (size_t)(icc_ * 32 + xh * 16) * PIX_ + iy_ * HW_ + srow; \
    _Pragma("unroll")                                                            \
    for (int i_ = 0; i_ < 16; ++i_) XR_[i_] = xs_[(size_t)i_ * PIX_];            \
  } } while (0)

#define WL(t_, W_) do { if ((t_) < NS) {                                         \
    const int iy_   = lo + ((t_) >> 3);                                          \
    const int icc_  = (t_) & 7;                                                  \
    const int tapb_ = (iy_ - py + 1) * 3;                                        \
    _Pragma("unroll")                                                            \
    for (int kx_ = 0; kx_ < 3; ++kx_) {                                          \
      const unsigned short* p_ =                                                 \
          wb2 + ((size_t)(((tapb_ + kx_) * 8 + icc_) * 16 + ogb) << 9) + wlo;    \
      _Pragma("unroll")                                                          \
      for (int i_ = 0; i_ < 4; ++i_)                                             \
        W_[kx_ * 4 + i_] = *(const short8*)(p_ + i_ * 512);                      \
    }                                                                            \
  } } while (0)

#define DSW(t_, XR_) do { if ((t_) < NS) {                                       \
    short8 p0_, p1_;                                                             \
    _Pragma("unroll")                                                            \
    for (int c_ = 0; c_ < 8; ++c_) {                                             \
      p0_[c_] = (short)f2bf(XR_[c_]);                                            \
      p1_[c_] = (short)f2bf(XR_[8 + c_]);                                        \
    }                                                                            \
    unsigned short* xd_ = &Xl[(t_) & 1][(srow + 1) * 32];                        \
    *(short8*)(&xd_[eX0])     = p0_;                                             \
    *(short8*)(&xd_[eX0 ^ 8]) = p1_;                                             \
  } } while (0)

#define MM(nb_, W_) do {                                                         \
    __builtin_amdgcn_s_setprio(1);                                               \
    _Pragma("unroll")                                                            \
    for (int kx_ = 0; kx_ < 3; ++kx_) {                                          \
      const int sB_ = (kx_ == 0) ? sB0 : (kx_ == 1) ? sB1 : sB2;                 \
      short8 bfr_[4];                                                            \
      _Pragma("unroll")                                                          \
      for (int j_ = 0; j_ < 4; ++j_)                                             \
        bfr_[j_] = *(const short8*)(                                             \
            &Xl[nb_][(wn * 64 + j_ * 16 + l15 + kx_) * 32 + (k0 ^ sB_)]);        \
      _Pragma("unroll")                                                          \
      for (int i_ = 0; i_ < 4; ++i_)                                             \
        _Pragma("unroll")                                                        \
        for (int j_ = 0; j_ < 4; ++j_)                                           \
          acc[i_][j_] = mfma_bf16(W_[kx_ * 4 + i_], bfr_[j_], acc[i_][j_]);      \
    }                                                                            \
    __builtin_amdgcn_s_setprio(0);                                               \
  } while (0)

  // prologue: X(0)->xrA, X(1)->xrB, W(0)->wA; write X(0) into buf0
  XL(0, xrA);
  XL(1, xrB);
  WL(0, wA);
  DSW(0, xrA);
  __syncthreads();

  for (int s = 0; s < NS; s += 2) {
    // even stage: compute buf0 with wA; prefetch X(s+2)->xrA, W(s+1)->wB
    XL(s + 2, xrA);
    WL(s + 1, wB);
    MM(0, wA);
    DSW(s + 1, xrB);                  // X(s+1) -> buf1
    __syncthreads();
    // odd stage: compute buf1 with wB; prefetch X(s+3)->xrB, W(s+2)->wA
    XL(s + 3, xrB);
    WL(s + 2, wA);
    MM(1, wB);
    DSW(s + 2, xrA);                  // X(s+2) -> buf0
    __syncthreads();
  }

#undef XL
#undef WL
#undef DSW
#undef MM

  // epilogue: bias + LeakyReLU(0.2)*sqrt(2); C/D: col=lane&15 (px), row=(lane>>4)*4+p (oc)
  const int row0 = (lane >> 4) * 4;
#pragma unroll
  for (int i = 0; i < 4; ++i) {
#pragma unroll
    for (int p = 0; p < 4; ++p) {
      const int oc = ot * 128 + wm * 64 + i * 16 + row0 + p;
      const float bvf = bias[oc];
#pragma unroll
      for (int j = 0; j < 4; ++j) {
        const int px = wn * 64 + j * 16 + l15;
        float v = acc[i][j][p] + bvf;
        v = (v >= 0.f ? v : 0.2f * v) * 1.41421356237f;
        out[((size_t)(b * OC_ + oc) * HW_ + py) * HW_ + px] = v;   // fp32 store
      }
    }
  }
}

extern "C" void kernel_launch(void* const* d_in, const int* in_sizes, int n_in,
                              void* d_out, int out_size, void* d_ws, size_t ws_size,
                              hipStream_t stream) {
  const float* x    = (const float*)d_in[0];   // fp32 [8,256,128,128]
  const float* code = (const float*)d_in[1];   // fp32 [8,256]
  const float* wgt  = (const float*)d_in[2];   // fp32 [256,256,3,3] flat
  const float* bias = (const float*)d_in[3];   // fp32 [256]

  const size_t WT_BYTES = (size_t)B_ * WT2_PER_B * 2;    // 9,437,184

  unsigned short* Wt2 = (unsigned short*)d_ws;
  float* norm2        = (float*)((char*)d_ws + WT_BYTES);

  k_zero<<<(B_ * OC_ + 255) / 256, 256, 0, stream>>>(norm2, B_ * OC_);
  k_norm<<<B_ * 9, 256, 0, stream>>>(wgt, code, norm2);
  k_modw<<<(B_ * WT2_PER_B) / 256, 256, 0, stream>>>(wgt, code, norm2, Wt2);
  k_conv<<<dim3(HW_, 2, B_), 256, 0, stream>>>(x, Wt2, bias, (float*)d_out);
}